// Round 11
// baseline (288.250 us; speedup 1.0000x reference)
//
#include <hip/hip_runtime.h>
#include <math.h>

#define BATCH 2
#define SEQ   2048
#define HID   1024
#define NHEAD 16
#define DHEAD 64
#define MROWS (BATCH*SEQ)      // 4096
#define SCALE_LOG2E 0.1803368801111244f   // 0.125 * log2(e)

typedef __attribute__((ext_vector_type(8))) short short8;
typedef __attribute__((ext_vector_type(4))) float floatx4;
typedef __attribute__((ext_vector_type(16))) float floatx16;
#define MFMA16(a,b,c) __builtin_amdgcn_mfma_f32_16x16x32_bf16(a,b,c,0,0,0)
#define MFMA32(a,b,c) __builtin_amdgcn_mfma_f32_32x32x16_bf16(a,b,c,0,0,0)

extern "C" __device__ float __ocml_native_exp2_f32(float);
#define EXP2F(x) __ocml_native_exp2_f32(x)

// global -> LDS direct DMA, 16B per lane (wave-uniform base + lane*16)
#define GLOBAL_TO_LDS16(g, l)                                                  \
    __builtin_amdgcn_global_load_lds(                                          \
        (const __attribute__((address_space(1))) void*)(g),                    \
        (__attribute__((address_space(3))) void*)(l), 16, 0, 0)

__device__ __forceinline__ unsigned short f2bf(float x) {   // round-half-up
    union { float f; unsigned u; } v; v.f = x;
    return (unsigned short)((v.u + 0x8000u) >> 16);
}
__device__ __forceinline__ float bf2f(unsigned short s) {
    union { unsigned u; float f; } v; v.u = ((unsigned)s) << 16;
    return v.f;
}
__device__ __forceinline__ unsigned pack_bf16(float lo, float hi) {
    union { float f; unsigned u; } a, b; a.f = lo; b.f = hi;
    return __builtin_amdgcn_perm(b.u + 0x8000u, a.u + 0x8000u, 0x07060302u);
}

// ---------------------------------------------------------------------------
// PREP (one launch): [0,6144) cvt fp32->bf16 q/k/v; [6144,7168) 4 wtrans
// tiles; [7168,7170) zero colsum.
// ---------------------------------------------------------------------------
__global__ __launch_bounds__(256) void prep_kernel(
    const float* __restrict__ qf, const float* __restrict__ kf,
    const float* __restrict__ vf,
    unsigned short* __restrict__ qa, unsigned short* __restrict__ ka,
    unsigned short* __restrict__ va,
    const float* __restrict__ W0, const float* __restrict__ W1,
    const float* __restrict__ W2, const float* __restrict__ W3,
    unsigned short* __restrict__ T0, unsigned short* __restrict__ T1,
    unsigned short* __restrict__ T2, unsigned short* __restrict__ T3,
    float* __restrict__ colsum)
{
    __shared__ float T[64][68];
    const int bid = blockIdx.x;
    const int tid = threadIdx.x;

    if (bid < 6144) {
        const int which = bid >> 11, pos = bid & 2047;
        const float* in; unsigned short* out;
        switch (which) {
            case 0:  in = qf; out = qa; break;
            case 1:  in = kf; out = ka; break;
            default: in = vf; out = va; break;
        }
        const size_t i = ((size_t)pos * 256 + tid) * 8;
        const float4 a = *(const float4*)&in[i];
        const float4 b = *(const float4*)&in[i + 4];
        uint4 u;
        u.x = pack_bf16(a.x, a.y); u.y = pack_bf16(a.z, a.w);
        u.z = pack_bf16(b.x, b.y); u.w = pack_bf16(b.z, b.w);
        *(uint4*)&out[i] = u;
    } else if (bid < 7168) {
        const int t = bid - 6144;
        const int z = t >> 8;
        const float* W; unsigned short* Wt;
        switch (z) {
            case 0:  W = W0; Wt = T0; break;
            case 1:  W = W1; Wt = T1; break;
            case 2:  W = W2; Wt = T2; break;
            default: W = W3; Wt = T3; break;
        }
        const int k0 = (t & 15) * 64, n0 = ((t >> 4) & 15) * 64;
#pragma unroll
        for (int it = 0; it < 4; it++) {
            const int id = it * 256 + tid;
            const int r = id >> 4, c4 = (id & 15) << 2;
            *(float4*)&T[r][c4] = *(const float4*)&W[(size_t)(k0 + r) * HID + n0 + c4];
        }
        __syncthreads();
#pragma unroll
        for (int it = 0; it < 2; it++) {
            const int id = it * 256 + tid;
            const int n = id >> 3, k8 = (id & 7) << 3;
            uint4 u;
            u.x = pack_bf16(T[k8 + 0][n], T[k8 + 1][n]);
            u.y = pack_bf16(T[k8 + 2][n], T[k8 + 3][n]);
            u.z = pack_bf16(T[k8 + 4][n], T[k8 + 5][n]);
            u.w = pack_bf16(T[k8 + 6][n], T[k8 + 7][n]);
            *(uint4*)&Wt[(size_t)(n0 + n) * HID + k0 + k8] = u;
        }
    } else {
        const int pos = bid - 7168;
        const size_t i = ((size_t)pos * 256 + tid) * 8;
        float4 z4; z4.x = 0.f; z4.y = 0.f; z4.z = 0.f; z4.w = 0.f;
        *(float4*)&colsum[i] = z4;
        *(float4*)&colsum[i + 4] = z4;
    }
}

// ---------------------------------------------------------------------------
// Fused Q/K/V projection GEMM (global_load_lds width 16, XOR-swizzled gather).
// z<2 -> row-major bf16; z==2 -> vt[b][h][d][seq] directly.
// ---------------------------------------------------------------------------
__global__ __launch_bounds__(256) void proj3_mfma_kernel(
    const unsigned short* __restrict__ A0, const unsigned short* __restrict__ A1,
    const unsigned short* __restrict__ A2,
    const unsigned short* __restrict__ B0, const unsigned short* __restrict__ B1,
    const unsigned short* __restrict__ B2,
    const float* __restrict__ bi0, const float* __restrict__ bi1,
    const float* __restrict__ bi2,
    unsigned short* __restrict__ C0, unsigned short* __restrict__ C1,
    unsigned short* __restrict__ vt)
{
    const unsigned short *Ab, *Bt; const float* bias;
    switch (blockIdx.z) {
        case 0:  Ab = A0; Bt = B0; bias = bi0; break;
        case 1:  Ab = A1; Bt = B1; bias = bi1; break;
        default: Ab = A2; Bt = B2; bias = bi2; break;
    }
    __shared__ unsigned short As[128 * 64];
    __shared__ unsigned short Bs[128 * 64];
    const int tid = threadIdx.x;
    const int w = tid >> 6, lane = tid & 63;
    const int c = lane & 15, quad = lane >> 4;
    const int m0 = blockIdx.x * 128, n0 = blockIdx.y * 128;
    const int wm = (w >> 1) * 64, wn = (w & 1) * 64;
    const int xr = c & 7;

    floatx4 acc[4][4];
#pragma unroll
    for (int i = 0; i < 4; i++)
#pragma unroll
        for (int j = 0; j < 4; j++) acc[i][j] = (floatx4){0.f, 0.f, 0.f, 0.f};

    for (int kc = 0; kc < HID; kc += 64) {
        __syncthreads();
#pragma unroll
        for (int it = 0; it < 4; it++) {
            const int id = it * 256 + tid;
            const int r = id >> 3;
            const int gsw = ((id & 7) ^ (r & 7)) << 3;
            GLOBAL_TO_LDS16(&Ab[(size_t)(m0 + r) * HID + kc + gsw], &As[id << 3]);
            GLOBAL_TO_LDS16(&Bt[(size_t)(n0 + r) * HID + kc + gsw], &Bs[id << 3]);
        }
        __syncthreads();
#pragma unroll
        for (int kk = 0; kk < 2; kk++) {
            short8 af[4], bf[4];
#pragma unroll
            for (int mt = 0; mt < 4; mt++)
                af[mt] = *(const short8*)
                    &As[((wm + mt * 16 + c) << 6) + (((kk * 4 + quad) ^ xr) << 3)];
#pragma unroll
            for (int nt = 0; nt < 4; nt++)
                bf[nt] = *(const short8*)
                    &Bs[((wn + nt * 16 + c) << 6) + (((kk * 4 + quad) ^ xr) << 3)];
#pragma unroll
            for (int mt = 0; mt < 4; mt++)
#pragma unroll
                for (int nt = 0; nt < 4; nt++)
                    acc[mt][nt] = MFMA16(af[mt], bf[nt], acc[mt][nt]);
        }
    }

    if (blockIdx.z < 2) {
        unsigned short* Cb = blockIdx.z == 0 ? C0 : C1;
#pragma unroll
        for (int nt = 0; nt < 4; nt++) {
            const int n = n0 + wn + nt * 16 + c;
            const float bb = bias[n];
#pragma unroll
            for (int mt = 0; mt < 4; mt++) {
                const int m = m0 + wm + mt * 16 + quad * 4;
#pragma unroll
                for (int r = 0; r < 4; r++)
                    Cb[(size_t)(m + r) * HID + n] = f2bf(acc[mt][nt][r] + bb);
            }
        }
    } else {
#pragma unroll
        for (int nt = 0; nt < 4; nt++) {
            const int n = n0 + wn + nt * 16 + c;
            const float bb = bias[n];
            const int h = n >> 6, d = n & 63;
#pragma unroll
            for (int mt = 0; mt < 4; mt++) {
                const int m = m0 + wm + mt * 16 + quad * 4;
                const int b = m >> 11, l = m & 2047;
                ushort4 u;
                u.x = f2bf(acc[mt][nt][0] + bb);
                u.y = f2bf(acc[mt][nt][1] + bb);
                u.z = f2bf(acc[mt][nt][2] + bb);
                u.w = f2bf(acc[mt][nt][3] + bb);
                *(ushort4*)&vt[((size_t)(b * NHEAD + h) * DHEAD + d) * SEQ + l] = u;
            }
        }
    }
}

// ---------------------------------------------------------------------------
// Final GEMM; gate applied in the epilogue (out[m] = gate ? acc+b : b).
// ---------------------------------------------------------------------------
__global__ __launch_bounds__(256) void gemm_gate_kernel(
    const unsigned short* __restrict__ Ab, const unsigned short* __restrict__ Bt,
    const float* __restrict__ bias,
    const float* __restrict__ gate_cs, const float* __restrict__ gate_th,
    float* __restrict__ Cf)
{
    __shared__ unsigned short As[128 * 64];
    __shared__ unsigned short Bs[128 * 64];
    const int tid = threadIdx.x;
    const int w = tid >> 6, lane = tid & 63;
    const int c = lane & 15, quad = lane >> 4;
    const int m0 = blockIdx.x * 128, n0 = blockIdx.y * 128;
    const int wm = (w >> 1) * 64, wn = (w & 1) * 64;
    const int xr = c & 7;

    floatx4 acc[4][4];
#pragma unroll
    for (int i = 0; i < 4; i++)
#pragma unroll
        for (int j = 0; j < 4; j++) acc[i][j] = (floatx4){0.f, 0.f, 0.f, 0.f};

    for (int kc = 0; kc < HID; kc += 64) {
        __syncthreads();
#pragma unroll
        for (int it = 0; it < 4; it++) {
            const int id = it * 256 + tid;
            const int r = id >> 3;
            const int gsw = ((id & 7) ^ (r & 7)) << 3;
            GLOBAL_TO_LDS16(&Ab[(size_t)(m0 + r) * HID + kc + gsw], &As[id << 3]);
            GLOBAL_TO_LDS16(&Bt[(size_t)(n0 + r) * HID + kc + gsw], &Bs[id << 3]);
        }
        __syncthreads();
#pragma unroll
        for (int kk = 0; kk < 2; kk++) {
            short8 af[4], bf[4];
#pragma unroll
            for (int mt = 0; mt < 4; mt++)
                af[mt] = *(const short8*)
                    &As[((wm + mt * 16 + c) << 6) + (((kk * 4 + quad) ^ xr) << 3)];
#pragma unroll
            for (int nt = 0; nt < 4; nt++)
                bf[nt] = *(const short8*)
                    &Bs[((wn + nt * 16 + c) << 6) + (((kk * 4 + quad) ^ xr) << 3)];
#pragma unroll
            for (int mt = 0; mt < 4; mt++)
#pragma unroll
                for (int nt = 0; nt < 4; nt++)
                    acc[mt][nt] = MFMA16(af[mt], bf[nt], acc[mt][nt]);
        }
    }

    float gmul[4][4];
#pragma unroll
    for (int mt = 0; mt < 4; mt++)
#pragma unroll
        for (int r = 0; r < 4; r++) {
            const int m = m0 + wm + mt * 16 + quad * 4 + r;
            gmul[mt][r] = (gate_cs[m] - gate_th[m]) > 0.f ? 1.f : 0.f;
        }

#pragma unroll
    for (int nt = 0; nt < 4; nt++) {
        const int n = n0 + wn + nt * 16 + c;
        const float bb = bias[n];
#pragma unroll
        for (int mt = 0; mt < 4; mt++) {
            const int m = m0 + wm + mt * 16 + quad * 4;
#pragma unroll
            for (int r = 0; r < 4; r++)
                Cf[(size_t)(m + r) * HID + n] = fmaf(acc[mt][nt][r], gmul[mt][r], bb);
        }
    }
}

// ---------------------------------------------------------------------------
// Pass 1, 32x32x16 MFMA: 128 q/block, 8 waves = 4 q-tiles x 2 k-halves.
// Q A-frags hoisted; each wave: one 32x32 S-tile (4 MFMAs), exp in C-layout,
// P -> per-wave LDS strip (stride 40, conflict-free), PV over OWN k-half
// (2 ksteps x 2 d-tiles) -> no mid-loop barrier. Partial O/Z combined once
// in the epilogue via LDS. XCD-swizzled grid, reg-dbuf staging.
// ---------------------------------------------------------------------------
__global__ __launch_bounds__(512, 4) void flash_mfma_kernel(
    const unsigned short* __restrict__ qb, const unsigned short* __restrict__ kb,
    const unsigned short* __restrict__ vt, const unsigned char* __restrict__ mask,
    unsigned short* __restrict__ att, float* __restrict__ zinv_out)
{
    const int n = blockIdx.x;
    const int xcd = n & 7, t = n >> 3;
    const int g = xcd + 8 * (t >> 4);
    const int qblk = t & 15;
    const int h = g & 15, b = g >> 4;
    const int q0 = qblk * 128;

    const int tid = threadIdx.x;
    const int w = tid >> 6, lane = tid & 63;
    const int l31 = lane & 31, lh = lane >> 5;
    const int qt = w & 3;             // q-tile (32 rows)
    const int kh = (w >> 2) * 32;     // k-half offset

    __shared__ unsigned short SM[19584];          // 39168 B
    unsigned short* Ks = SM;                      // [64][72]  K[k][d]
    unsigned short* Vs = SM + 4608;               // [64][72]  V[d][k]
    unsigned short* Ps = SM + 9216;               // [8 waves][32][40]
    float* mbf = (float*)(SM + 19456);            // [64]
    unsigned short* Qs = SM;                      // staging alias [128][72]

    const size_t hoff = (size_t)h * DHEAD;
#pragma unroll
    for (int it = 0; it < 2; it++) {
        const int gg = it * 512 + tid;
        const int r = gg >> 3, c8 = (gg & 7) << 3;
        *(uint4*)&Qs[r * 72 + c8] =
            *(const uint4*)&qb[(size_t)(b * SEQ + q0 + r) * HID + hoff + c8];
    }
    __syncthreads();
    short8 aq[4];
#pragma unroll
    for (int d0 = 0; d0 < 4; d0++)
        aq[d0] = *(const short8*)&Qs[(qt * 32 + l31) * 72 + d0 * 16 + lh * 8];

    floatx16 acc0, acc1;
    float zp[16];
#pragma unroll
    for (int r = 0; r < 16; r++) { acc0[r] = 0.f; acc1[r] = 0.f; zp[r] = 0.f; }

    const size_t vtbase = (size_t)(b * NHEAD + h) * DHEAD * SEQ;
    const int sr = tid >> 3, sc8 = (tid & 7) << 3;
    uint4 kreg = *(const uint4*)&kb[(size_t)(b * SEQ + sr) * HID + hoff + sc8];
    uint4 vreg = *(const uint4*)&vt[vtbase + (size_t)sr * SEQ + sc8];
    float mreg = 0.f;
    if (tid < 64) mreg = mask[(size_t)b * SEQ + tid] ? -1e9f : 0.f;

    unsigned short* Pw = Ps + w * 1280;           // [32][40]

    for (int kc = 0; kc < SEQ; kc += 64) {
        __syncthreads();
        *(uint4*)&Ks[sr * 72 + sc8] = kreg;
        *(uint4*)&Vs[sr * 72 + sc8] = vreg;
        if (tid < 64) mbf[tid] = mreg;
        __syncthreads();
        if (kc + 64 < SEQ) {
            kreg = *(const uint4*)&kb[(size_t)(b * SEQ + kc + 64 + sr) * HID + hoff + sc8];
            vreg = *(const uint4*)&vt[vtbase + (size_t)sr * SEQ + kc + 64 + sc8];
            if (tid < 64) mreg = mask[(size_t)b * SEQ + kc + 64 + tid] ? -1e9f : 0.f;
        }

        // S-tile (32q x 32k): D col = k-col = kh+l31, row = f(reg)+4*lh
        floatx16 s;
#pragma unroll
        for (int r = 0; r < 16; r++) s[r] = 0.f;
#pragma unroll
        for (int d0 = 0; d0 < 4; d0++) {
            const short8 bk = *(const short8*)&Ks[(kh + l31) * 72 + d0 * 16 + lh * 8];
            s = MFMA32(aq[d0], bk, s);
        }
        const float mb = mbf[kh + l31];
#pragma unroll
        for (int r = 0; r < 16; r++) {
            const float p = EXP2F(fmaf(s[r], SCALE_LOG2E, mb));
            zp[r] += p;
            const int row = (r & 3) + 8 * (r >> 2) + 4 * lh;
            Pw[row * 40 + l31] = f2bf(p);
        }

        // PV over own k-half: A = P[q][k_local], B = V[k][d]
#pragma unroll
        for (int k0 = 0; k0 < 2; k0++) {
            const short8 ap = *(const short8*)&Pw[l31 * 40 + k0 * 16 + lh * 8];
            const short8 bv0 = *(const short8*)&Vs[l31 * 72 + kh + k0 * 16 + lh * 8];
            const short8 bv1 = *(const short8*)&Vs[(32 + l31) * 72 + kh + k0 * 16 + lh * 8];
            acc0 = MFMA32(ap, bv0, acc0);
            acc1 = MFMA32(ap, bv1, acc1);
        }
    }

    // reduce zp over the 32 k-cols this wave owns (lanes within each half)
#pragma unroll
    for (int r = 0; r < 16; r++) {
        float z = zp[r];
        z += __shfl_xor(z, 1, 64);  z += __shfl_xor(z, 2, 64);
        z += __shfl_xor(z, 4, 64);  z += __shfl_xor(z, 8, 64);
        z += __shfl_xor(z, 16, 64);
        zp[r] = z;
    }

    __syncthreads();                              // loop LDS reads complete
    float* Osh = (float*)SM;                      // [4][32][64] f32 = 32 KB
    float* Zsh = (float*)((char*)SM + 32768);     // [128]
    if (kh == 0) {
#pragma unroll
        for (int r = 0; r < 16; r++) {
            const int row = (r & 3) + 8 * (r >> 2) + 4 * lh;
            Osh[(qt * 32 + row) * 64 + l31]      = acc0[r];
            Osh[(qt * 32 + row) * 64 + 32 + l31] = acc1[r];
            if (l31 == 0) Zsh[qt * 32 + row] = zp[r];
        }
    }
    __syncthreads();
    if (kh == 32) {
#pragma unroll
        for (int r = 0; r < 16; r++) {
            const int row = (r & 3) + 8 * (r >> 2) + 4 * lh;
            const float zt = zp[r] + Zsh[qt * 32 + row];
            const float zi = 1.0f / (zt + 1e-30f);
            const float o0 = (acc0[r] + Osh[(qt * 32 + row) * 64 + l31]) * zi;
            const float o1 = (acc1[r] + Osh[(qt * 32 + row) * 64 + 32 + l31]) * zi;
            const size_t arow = (size_t)(b * SEQ + q0 + qt * 32 + row) * HID + hoff;
            att[arow + l31]      = f2bf(o0);
            att[arow + 32 + l31] = f2bf(o1);
            if (l31 == 0)
                zinv_out[(size_t)(b * NHEAD + h) * SEQ + q0 + qt * 32 + row] = zi;
        }
    }
}

// ---------------------------------------------------------------------------
// Fused pass 2: blocks [0,512) colsum via 32x32x16 (A=K hoisted, 4 B-frag
// reads/chunk, atomicAdd combines q-halves and heads); [512,1024) threshold.
// ---------------------------------------------------------------------------
__global__ __launch_bounds__(512, 4) void colsum_thr_kernel(
    const unsigned short* __restrict__ qb, const unsigned short* __restrict__ kb,
    const unsigned char* __restrict__ mask, const float* __restrict__ zinv,
    float* __restrict__ colsum,
    const float* __restrict__ Wt, const float* __restrict__ bt,
    float* __restrict__ thr)
{
    __shared__ unsigned short SM[9216];           // 18432 B
    const int tid = threadIdx.x;
    const int w = tid >> 6, lane = tid & 63;

    if (blockIdx.x >= 512) {                      // ---- threshold branch
        const int row = (blockIdx.x - 512) * 8 + w;
        const unsigned short* qr = qb + (size_t)row * HID;
        const unsigned short* kr = kb + (size_t)row * HID;
        float s = 0.f;
#pragma unroll
        for (int ii = 0; ii < 2; ii++) {
            const int base = ii * 512 + lane * 8;
            const ushort4 q0 = *(const ushort4*)&qr[base];
            const ushort4 q1 = *(const ushort4*)&qr[base + 4];
            const ushort4 k0 = *(const ushort4*)&kr[base];
            const ushort4 k1 = *(const ushort4*)&kr[base + 4];
            const float4 w0 = *(const float4*)&Wt[base];
            const float4 w1 = *(const float4*)&Wt[base + 4];
            s += bf2f(q0.x) * bf2f(k0.x) * w0.x + bf2f(q0.y) * bf2f(k0.y) * w0.y +
                 bf2f(q0.z) * bf2f(k0.z) * w0.z + bf2f(q0.w) * bf2f(k0.w) * w0.w +
                 bf2f(q1.x) * bf2f(k1.x) * w1.x + bf2f(q1.y) * bf2f(k1.y) * w1.y +
                 bf2f(q1.z) * bf2f(k1.z) * w1.z + bf2f(q1.w) * bf2f(k1.w) * w1.w;
        }
#pragma unroll
        for (int off = 32; off > 0; off >>= 1) s += __shfl_xor(s, off, 64);
        if (lane == 0) thr[row] = s + bt[0];
        return;
    }

    // ---- colsum branch: 128 k-cols, 8 waves = 4 k-tiles x 2 q-halves
    const int n = blockIdx.x;
    const int xcd = n & 7, t = n >> 3;
    const int g = xcd + 8 * (t >> 4);
    const int h = g & 15, b = g >> 4;
    const int k0 = (t & 15) * 128;
    const int l31 = lane & 31, lh = lane >> 5;
    const int kt = w & 3;             // k-tile (32 cols)
    const int qh = (w >> 2) * 32;     // q-half offset

    unsigned short* Qs = SM;                      // steady [64][72]
    float* zs = (float*)(SM + 4608);              // [64]
    unsigned short* Kst = SM;                     // staging alias [128][72]

    const size_t hoff = (size_t)h * DHEAD;
#pragma unroll
    for (int it = 0; it < 2; it++) {
        const int gg = it * 512 + tid;
        const int r = gg >> 3, c8 = (gg & 7) << 3;
        *(uint4*)&Kst[r * 72 + c8] =
            *(const uint4*)&kb[(size_t)(b * SEQ + k0 + r) * HID + hoff + c8];
    }
    __syncthreads();
    short8 ak[4];
#pragma unroll
    for (int d0 = 0; d0 < 4; d0++)
        ak[d0] = *(const short8*)&Kst[(kt * 32 + l31) * 72 + d0 * 16 + lh * 8];
    float mb[16];
#pragma unroll
    for (int r = 0; r < 16; r++) {
        const int row = (r & 3) + 8 * (r >> 2) + 4 * lh;
        mb[r] = mask[(size_t)b * SEQ + k0 + kt * 32 + row] ? -1e9f : 0.f;
    }

    float cs[16];
#pragma unroll
    for (int r = 0; r < 16; r++) cs[r] = 0.f;
    const size_t zbase = (size_t)(b * NHEAD + h) * SEQ;

    const int sr = tid >> 3, sc8 = (tid & 7) << 3;
    uint4 qreg = *(const uint4*)&qb[(size_t)(b * SEQ + sr) * HID + hoff + sc8];
    float zreg = 0.f;
    if (tid < 64) zreg = zinv[zbase + tid];

    for (int qc = 0; qc < SEQ; qc += 64) {
        __syncthreads();
        *(uint4*)&Qs[sr * 72 + sc8] = qreg;
        if (tid < 64) zs[tid] = zreg;
        __syncthreads();
        if (qc + 64 < SEQ) {
            qreg = *(const uint4*)&qb[(size_t)(b * SEQ + qc + 64 + sr) * HID + hoff + sc8];
            if (tid < 64) zreg = zinv[zbase + qc + 64 + tid];
        }

        // S^T tile (32k x 32q): D col = q-col = qh+l31, row = k within tile
        floatx16 s;
#pragma unroll
        for (int r = 0; r < 16; r++) s[r] = 0.f;
#pragma unroll
        for (int d0 = 0; d0 < 4; d0++) {
            const short8 bq = *(const short8*)&Qs[(qh + l31) * 72 + d0 * 16 + lh * 8];
            s = MFMA32(ak[d0], bq, s);
        }
        const float zi = zs[qh + l31];
#pragma unroll
        for (int r = 0; r < 16; r++)
            cs[r] += EXP2F(fmaf(s[r], SCALE_LOG2E, mb[r])) * zi;
    }

#pragma unroll
    for (int r = 0; r < 16; r++) {
        float v = cs[r];
        v += __shfl_xor(v, 1, 64);  v += __shfl_xor(v, 2, 64);
        v += __shfl_xor(v, 4, 64);  v += __shfl_xor(v, 8, 64);
        v += __shfl_xor(v, 16, 64);
        if (l31 == 0) {
            const int row = (r & 3) + 8 * (r >> 2) + 4 * lh;
            atomicAdd(&colsum[(size_t)b * SEQ + k0 + kt * 32 + row], v);
        }
    }
}

// ---------------------------------------------------------------------------
extern "C" void kernel_launch(void* const* d_in, const int* in_sizes, int n_in,
                              void* d_out, int out_size, void* d_ws, size_t ws_size,
                              hipStream_t stream)
{
    const float* v  = (const float*)d_in[0];
    const float* k  = (const float*)d_in[1];
    const float* q  = (const float*)d_in[2];
    const unsigned char* mask = (const unsigned char*)d_in[3];
    const float* Wv = (const float*)d_in[4];
    const float* bv = (const float*)d_in[5];
    const float* Wk = (const float*)d_in[6];
    const float* bk = (const float*)d_in[7];
    const float* Wq = (const float*)d_in[8];
    const float* bq = (const float*)d_in[9];
    const float* Wt = (const float*)d_in[10];
    const float* bt = (const float*)d_in[11];
    const float* Wm = (const float*)d_in[12];
    const float* bm = (const float*)d_in[13];
    float* out = (float*)d_out;

    const size_t NE = (size_t)MROWS * HID;
    const size_t WE = (size_t)HID * HID;
    unsigned short* qa   = (unsigned short*)d_ws;
    unsigned short* ka   = qa  + NE;
    unsigned short* va   = ka  + NE;
    unsigned short* qp   = va  + NE;
    unsigned short* kp   = qp  + NE;
    unsigned short* vtb  = kp  + NE;
    unsigned short* WqT  = vtb + NE;
    unsigned short* WkT  = WqT + WE;
    unsigned short* WvT  = WkT + WE;
    unsigned short* WmT  = WvT + WE;
    float* thr    = (float*)(WmT + WE);
    float* zinv   = thr  + MROWS;
    float* colsum = zinv + (size_t)BATCH * NHEAD * SEQ;
    // attb aliases qa: qa is only read by proj3 (z=0), dead before flash runs
    unsigned short* attb = qa;

    prep_kernel<<<7170, 256, 0, stream>>>(q, k, v, qa, ka, va,
                                          Wq, Wk, Wv, Wm, WqT, WkT, WvT, WmT,
                                          colsum);

    proj3_mfma_kernel<<<dim3(MROWS / 128, HID / 128, 3), 256, 0, stream>>>(
        qa, ka, va, WqT, WkT, WvT, bq, bk, bv, qp, kp, vtb);

    flash_mfma_kernel<<<BATCH * NHEAD * (SEQ / 128), 512, 0, stream>>>(
        qp, kp, vtb, mask, attb, zinv);

    colsum_thr_kernel<<<1024, 512, 0, stream>>>(
        qp, kp, mask, zinv, colsum, Wt, bt, thr);

    gemm_gate_kernel<<<dim3(MROWS / 128, HID / 128), 256, 0, stream>>>(
        attb, WmT, bm, colsum, thr, out);
}